// Round 4
// baseline (228.839 us; speedup 1.0000x reference)
//
#include <hip/hip_runtime.h>
#include <hip/hip_bf16.h>
#include <stdint.h>

// Problem constants
#define N_NODES 8192
#define N_EDGES 16384
#define N_GRAPHS 512
#define IN_DIM 235
#define H_DIM 64
#define ED_DIM 52
#define HID1 128          // edge-MLP hidden width (W1 rows)
#define KP 256            // K padded 235 -> 256 for MFMA tiling
#define NB 3328           // ED_DIM * H_DIM = P column count
#define NBE 3456          // NB + 64 (root) + 64 (bc) extra GEMM columns

typedef __bf16 bf16x8 __attribute__((ext_vector_type(8)));
typedef float f32x4 __attribute__((ext_vector_type(4)));

static __device__ inline unsigned short f2bf(float f) {
    union { float f; unsigned u; } v; v.f = f;
    unsigned r = v.u + 0x7FFFu + ((v.u >> 16) & 1u);   // RNE
    return (unsigned short)(r >> 16);
}
static __device__ inline float bf2f(unsigned short s) {
    union { unsigned u; float f; } v; v.u = ((unsigned)s) << 16;
    return v.f;
}

// ---------------------------------------------------------------------------
// K0a: compose edge-MLP weights: Bt[p=(d*64+h)][i] = sum_k W2[(i*64+h)*128+k]*W1[k*52+d]
__global__ __launch_bounds__(256) void k_build_bt(const float* __restrict__ W1,
                                                  const float* __restrict__ W2,
                                                  unsigned short* __restrict__ Bt) {
    __shared__ float w1s[13 * HID1];          // [dd][k]
    __shared__ float w2s[64 * 132];           // [h][k] padded to 132
    const int i = blockIdx.x;                 // 0..234
    const int by = blockIdx.y;                // 0..3
    const int t = threadIdx.x;
    const int dbase = by * 13;
    for (int j = t; j < 13 * HID1; j += 256) {
        const int dd = j >> 7, k = j & 127;
        w1s[j] = W1[k * ED_DIM + dbase + dd];
    }
    const float* w2src = W2 + (size_t)i * 64 * HID1;
    for (int j = t; j < 64 * HID1; j += 256) w2s[(j >> 7) * 132 + (j & 127)] = w2src[j];
    __syncthreads();
    const int pend = by * 832 + 832;
    for (int p = by * 832 + t; p < pend; p += 256) {
        const int dd = (p >> 6) - dbase, h = p & 63;
        const float4* w1v = (const float4*)&w1s[dd * HID1];
        const float4* w2v = (const float4*)&w2s[h * 132];
        float acc = 0.f;
        #pragma unroll
        for (int k4 = 0; k4 < HID1 / 4; ++k4) {
            const float4 a = w1v[k4], b = w2v[k4];
            acc += a.x * b.x + a.y * b.y + a.z * b.z + a.w * b.w;
        }
        Bt[(size_t)p * KP + i] = f2bf(acc);
    }
}

// K0b: composed bias bc[j] = b2[j] + sum_k W2[j,k]*b1[k]
__global__ __launch_bounds__(256) void k_build_bc(const float* __restrict__ W2,
                                                  const float* __restrict__ b1,
                                                  const float* __restrict__ b2,
                                                  float* __restrict__ bc) {
    const int j = blockIdx.x * 256 + threadIdx.x;
    if (j >= IN_DIM * H_DIM) return;
    float acc = b2[j];
    const float* w = W2 + (size_t)j * HID1;
    #pragma unroll 8
    for (int k = 0; k < HID1; ++k) acc += w[k] * b1[k];
    bc[j] = acc;
}

// K0c: extra GEMM columns: 3328+j (j<64) = root col j; 3392+j = bc col j.
__global__ __launch_bounds__(256) void k_build_ext(const float* __restrict__ root,
                                                   const float* __restrict__ bc,
                                                   unsigned short* __restrict__ Bt) {
    const int j = blockIdx.x;        // 0..127
    const int i = threadIdx.x;       // 0..255
    if (i >= IN_DIM) return;
    const float v = (j < 64) ? root[i * H_DIM + j] : bc[i * H_DIM + (j - 64)];
    Bt[(size_t)(NB + j) * KP + i] = f2bf(v);
}

// K1: x (fp32, [8192,235]) -> A (bf16, [8192,256] zero-padded)
__global__ __launch_bounds__(256) void k_build_a(const float* __restrict__ x,
                                                 unsigned short* __restrict__ A) {
    const int j = blockIdx.x * 256 + threadIdx.x;
    const int n = j >> 8, i = j & 255;
    A[j] = (i < IN_DIM) ? f2bf(x[n * IN_DIM + i]) : (unsigned short)0;
}

// ---------------------------------------------------------------------------
// K2: [8192,256] x [256,3456] GEMM, PREFETCH-AFTER-BARRIER double buffer.
// Loop: barrier (drains prefetch issued LAST iter, overlapped with last iter's
// compute) -> issue prefetch for k+1 -> compute k. Exposed latency per iter is
// max(0, load_latency - compute) instead of full latency (old 2-barrier form).
// XOR source swizzle keeps fragment ds_read_b128 conflict-free.
// MFMA operands swapped -> transposed D -> packed row-major stores.
__global__ __launch_bounds__(256) void k_gemm(const unsigned short* __restrict__ A,
                                              const unsigned short* __restrict__ Bt,
                                              unsigned short* __restrict__ P,
                                              float* __restrict__ agg,
                                              float* __restrict__ xb2,
                                              const float* __restrict__ conv_b) {
    __shared__ unsigned short As[2 * 128 * 32];
    __shared__ unsigned short Bs[2 * 128 * 32];
    const int t = threadIdx.x;
    const int m0 = blockIdx.y * 128, n0 = blockIdx.x * 128;
    const int wid = t >> 6, lane = t & 63;
    const int wm = wid >> 1, wn = wid & 1;
    const int q = lane >> 4, r16 = lane & 15;

    f32x4 acc[4][4] = {};

    // stage K-tile k0 into buffer `buf` (wave-uniform LDS base, lane scatters *16B)
    auto stage = [&](int k0, int buf) {
        #pragma unroll
        for (int r = 0; r < 2; ++r) {
            const int idx = r * 256 + t;              // physical 16B slot
            const int row = idx >> 2;
            const int lgrp = ((idx & 3) ^ ((row >> 1) & 3)) * 8;  // logical k-chunk
            const unsigned short* ga = &A[(size_t)(m0 + row) * KP + k0 + lgrp];
            const unsigned short* gb = &Bt[(size_t)(n0 + row) * KP + k0 + lgrp];
            char* la = (char*)As + buf * 8192 + r * 4096 + wid * 1024;
            char* lb = (char*)Bs + buf * 8192 + r * 4096 + wid * 1024;
            __builtin_amdgcn_global_load_lds(
                (const __attribute__((address_space(1))) unsigned int*)ga,
                (__attribute__((address_space(3))) unsigned int*)la, 16, 0, 0);
            __builtin_amdgcn_global_load_lds(
                (const __attribute__((address_space(1))) unsigned int*)gb,
                (__attribute__((address_space(3))) unsigned int*)lb, 16, 0, 0);
        }
    };

    stage(0, 0);
    const int pcq = (q ^ ((r16 >> 1) & 3)) * 8;       // physical chunk for logical q
    #pragma unroll
    for (int it = 0; it < 8; ++it) {
        __syncthreads();                              // drains prefetch for buf[it&1]
        if (it < 7) stage((it + 1) * 32, (it + 1) & 1);
        const int bo = (it & 1) * 4096;               // buffer offset in shorts
        bf16x8 af[4], bfr[4];
        #pragma unroll
        for (int mi = 0; mi < 4; ++mi)
            af[mi] = *(const bf16x8*)(&As[bo + (wm * 64 + mi * 16 + r16) * 32 + pcq]);
        #pragma unroll
        for (int ni = 0; ni < 4; ++ni)
            bfr[ni] = *(const bf16x8*)(&Bs[bo + (wn * 64 + ni * 16 + r16) * 32 + pcq]);
        #pragma unroll
        for (int mi = 0; mi < 4; ++mi)
            #pragma unroll
            for (int ni = 0; ni < 4; ++ni)
                acc[mi][ni] = __builtin_amdgcn_mfma_f32_16x16x32_bf16(
                    bfr[ni], af[mi], acc[mi][ni], 0, 0, 0);   // transposed D
    }

    // Transposed D: lane (q,r16) holds rows m = mi*16+r16, cols n = ni*16+q*4+rr
    if (n0 < NB) {
        #pragma unroll
        for (int mi = 0; mi < 4; ++mi)
            #pragma unroll
            for (int ni = 0; ni < 4; ++ni) {
                const int row = m0 + wm * 64 + mi * 16 + r16;
                const int col = n0 + wn * 64 + ni * 16 + q * 4;
                union { unsigned short us[4]; uint2 u2; } pk;
                #pragma unroll
                for (int rr = 0; rr < 4; ++rr) pk.us[rr] = f2bf(acc[mi][ni][rr]);
                *(uint2*)(&P[(size_t)row * NB + col]) = pk.u2;
            }
    } else {
        #pragma unroll
        for (int mi = 0; mi < 4; ++mi)
            #pragma unroll
            for (int ni = 0; ni < 4; ++ni) {
                const int row = m0 + wm * 64 + mi * 16 + r16;
                const int cl = ni * 16 + q * 4;       // 0..63 within the half
                if (wn == 0) {
                    const float4 cb = *(const float4*)&conv_b[cl];
                    float4 v;
                    v.x = acc[mi][ni][0] + cb.x; v.y = acc[mi][ni][1] + cb.y;
                    v.z = acc[mi][ni][2] + cb.z; v.w = acc[mi][ni][3] + cb.w;
                    *(float4*)(&agg[row * H_DIM + cl]) = v;
                } else {
                    float4 v;
                    v.x = acc[mi][ni][0]; v.y = acc[mi][ni][1];
                    v.z = acc[mi][ni][2]; v.w = acc[mi][ni][3];
                    *(float4*)(&xb2[row * H_DIM + cl]) = v;
                }
            }
    }
}

// ---------------------------------------------------------------------------
// K4: per edge (one wave, lane=h). FULL unroll: all 52 P-row loads in flight
// (one latency payment per edge, not 13); ea preloaded as 13 float4.
__global__ __launch_bounds__(256) void k_edge(const int* __restrict__ ei,
                                              const float* __restrict__ ea,
                                              const unsigned short* __restrict__ P,
                                              const float* __restrict__ xb2,
                                              float* __restrict__ agg) {
    const int e = (blockIdx.x * 256 + threadIdx.x) >> 6;
    const int h = threadIdx.x & 63;
    if (e >= N_EDGES) return;
    const int s = ei[e], dst = ei[N_EDGES + e];
    const unsigned short* Pr = P + (size_t)s * NB + h;
    const float* ear = ea + (size_t)e * ED_DIM;

    float eav[ED_DIM];
    #pragma unroll
    for (int d4 = 0; d4 < ED_DIM / 4; ++d4)
        *(float4*)&eav[d4 * 4] = *(const float4*)&ear[d4 * 4];

    unsigned short pv[ED_DIM];
    #pragma unroll
    for (int d = 0; d < ED_DIM; ++d) pv[d] = Pr[d * H_DIM];

    float acc = xb2[s * H_DIM + h];
    #pragma unroll
    for (int d = 0; d < ED_DIM; ++d) acc += eav[d] * bf2f(pv[d]);
    atomicAdd(&agg[dst * H_DIM + h], acc);
}

// K5: out = relu(agg); mean-pool accumulate per graph
__global__ __launch_bounds__(256) void k_pool(const float* __restrict__ agg,
                                              const int* __restrict__ batch,
                                              float* __restrict__ psum,
                                              float* __restrict__ pcnt) {
    const int n = (blockIdx.x * 256 + threadIdx.x) >> 6;
    const int h = threadIdx.x & 63;
    if (n >= N_NODES) return;
    const float v = fmaxf(agg[n * H_DIM + h], 0.f);
    const int g = batch[n];
    atomicAdd(&psum[g * H_DIM + h], v);
    if (h == 0) atomicAdd(&pcnt[g], 1.0f);
}

// K6: MLP head, one block per graph
__global__ __launch_bounds__(256) void k_head(const float* __restrict__ psum,
                                              const float* __restrict__ pcnt,
                                              const float* __restrict__ fw1, const float* __restrict__ fb1,
                                              const float* __restrict__ fw2, const float* __restrict__ fb2,
                                              const float* __restrict__ fw3, const float* __restrict__ fb3,
                                              const float* __restrict__ fw4, const float* __restrict__ fb4,
                                              float* __restrict__ out) {
    __shared__ float sp[64], s1[128], s2[256], s3[128];
    const int g = blockIdx.x, t = threadIdx.x;
    if (t < 64) sp[t] = psum[g * 64 + t] / fmaxf(pcnt[g], 1.0f);
    __syncthreads();
    if (t < 128) {
        float a = fb1[t];
        const float* w = fw1 + t * 64;
        #pragma unroll 8
        for (int k = 0; k < 64; ++k) a += sp[k] * w[k];
        s1[t] = fmaxf(a, 0.f);
    }
    __syncthreads();
    {
        float a = fb2[t];
        const float* w = fw2 + t * 128;
        #pragma unroll 8
        for (int k = 0; k < 128; ++k) a += s1[k] * w[k];
        s2[t] = fmaxf(a, 0.f);
    }
    __syncthreads();
    if (t < 128) {
        float a = fb3[t];
        const float* w = fw3 + t * 256;
        #pragma unroll 8
        for (int k = 0; k < 256; ++k) a += s2[k] * w[k];
        s3[t] = fmaxf(a, 0.f);
    }
    __syncthreads();
    if (t < 64) {
        float p = s3[t] * fw4[t] + s3[t + 64] * fw4[t + 64];
        #pragma unroll
        for (int off = 32; off > 0; off >>= 1) p += __shfl_down(p, off);
        if (t == 0) out[g] = p + fb4[0];
    }
}

// ---------------------------------------------------------------------------
extern "C" void kernel_launch(void* const* d_in, const int* in_sizes, int n_in,
                              void* d_out, int out_size, void* d_ws, size_t ws_size,
                              hipStream_t stream) {
    const float* x      = (const float*)d_in[0];
    const int*   ei     = (const int*)d_in[1];
    const float* ea     = (const float*)d_in[2];
    const int*   batch  = (const int*)d_in[3];
    const float* W1     = (const float*)d_in[4];
    const float* b1     = (const float*)d_in[5];
    const float* W2     = (const float*)d_in[6];
    const float* b2     = (const float*)d_in[7];
    const float* root   = (const float*)d_in[8];
    const float* conv_b = (const float*)d_in[9];
    const float* fw1 = (const float*)d_in[10]; const float* fb1 = (const float*)d_in[11];
    const float* fw2 = (const float*)d_in[12]; const float* fb2 = (const float*)d_in[13];
    const float* fw3 = (const float*)d_in[14]; const float* fb3 = (const float*)d_in[15];
    const float* fw4 = (const float*)d_in[16]; const float* fb4 = (const float*)d_in[17];
    float* out = (float*)d_out;

    char* ws = (char*)d_ws;
    // workspace layout (16B-aligned), total ~64.9 MB
    unsigned short* A   = (unsigned short*)(ws);             // 8192*256*2   = 4,194,304
    unsigned short* Bt  = (unsigned short*)(ws + 4194304);   // 3456*256*2   = 1,769,472
    unsigned short* P   = (unsigned short*)(ws + 5963776);   // 8192*3328*2  = 54,525,952
    float* agg  = (float*)(ws + 60489728);                   // 8192*64*4    = 2,097,152
    float* xb2  = (float*)(ws + 62586880);                   // 8192*64*4    = 2,097,152
    float* bc   = (float*)(ws + 64684032);                   // 15040*4      = 60,160
    float* psum = (float*)(ws + 64744192);                   // 512*64*4     = 131,072
    float* pcnt = (float*)(ws + 64875264);                   // 512*4        = 2,048

    // Bt must start zeroed (pad cols i>=235); psum/pcnt contiguous -> one memset
    hipMemsetAsync(Bt, 0, (size_t)NBE * KP * sizeof(unsigned short), stream);
    hipMemsetAsync(psum, 0, (size_t)(N_GRAPHS * H_DIM + N_GRAPHS) * sizeof(float), stream);

    k_build_bc<<<dim3((IN_DIM * H_DIM + 255) / 256), dim3(256), 0, stream>>>(W2, b1, b2, bc);
    k_build_bt<<<dim3(IN_DIM, 4), dim3(256), 0, stream>>>(W1, W2, Bt);
    k_build_ext<<<dim3(128), dim3(256), 0, stream>>>(root, bc, Bt);
    k_build_a<<<dim3(N_NODES), dim3(256), 0, stream>>>(x, A);
    k_gemm<<<dim3(NBE / 128, N_NODES / 128), dim3(256), 0, stream>>>(A, Bt, P, agg, xb2, conv_b);
    k_edge<<<dim3(N_EDGES / 4), dim3(256), 0, stream>>>(ei, ea, P, xb2, agg);
    k_pool<<<dim3(N_NODES / 4), dim3(256), 0, stream>>>(agg, batch, psum, pcnt);
    k_head<<<dim3(N_GRAPHS), dim3(256), 0, stream>>>(psum, pcnt, fw1, fb1, fw2, fb2, fw3, fb3, fw4, fb4, out);
}

// Round 5
// 218.092 us; speedup vs baseline: 1.0493x; 1.0493x over previous
//
#include <hip/hip_runtime.h>
#include <hip/hip_bf16.h>
#include <stdint.h>

// Problem constants
#define N_NODES 8192
#define N_EDGES 16384
#define N_GRAPHS 512
#define IN_DIM 235
#define H_DIM 64
#define ED_DIM 52
#define HID1 128          // edge-MLP hidden width (W1 rows)
#define KP 256            // K padded 235 -> 256 for MFMA tiling
#define NB 3328           // ED_DIM * H_DIM = P column count
#define NBE 3456          // NB + 64 (root) + 64 (bc) live GEMM columns
#define NBP 3584          // padded to 14 x 256 tiles (cols 3456..3583 zero)

typedef __bf16 bf16x8 __attribute__((ext_vector_type(8)));
typedef float f32x4 __attribute__((ext_vector_type(4)));

static __device__ inline unsigned short f2bf(float f) {
    union { float f; unsigned u; } v; v.f = f;
    unsigned r = v.u + 0x7FFFu + ((v.u >> 16) & 1u);   // RNE
    return (unsigned short)(r >> 16);
}
static __device__ inline float bf2f(unsigned short s) {
    union { unsigned u; float f; } v; v.u = ((unsigned)s) << 16;
    return v.f;
}

// ---------------------------------------------------------------------------
// K0a: compose edge-MLP weights: Bt[p=(d*64+h)][i] = sum_k W2[(i*64+h)*128+k]*W1[k*52+d]
__global__ __launch_bounds__(256) void k_build_bt(const float* __restrict__ W1,
                                                  const float* __restrict__ W2,
                                                  unsigned short* __restrict__ Bt) {
    __shared__ float w1s[13 * HID1];          // [dd][k]
    __shared__ float w2s[64 * 132];           // [h][k] padded to 132
    const int i = blockIdx.x;                 // 0..234
    const int by = blockIdx.y;                // 0..3
    const int t = threadIdx.x;
    const int dbase = by * 13;
    for (int j = t; j < 13 * HID1; j += 256) {
        const int dd = j >> 7, k = j & 127;
        w1s[j] = W1[k * ED_DIM + dbase + dd];
    }
    const float* w2src = W2 + (size_t)i * 64 * HID1;
    for (int j = t; j < 64 * HID1; j += 256) w2s[(j >> 7) * 132 + (j & 127)] = w2src[j];
    __syncthreads();
    const int pend = by * 832 + 832;
    for (int p = by * 832 + t; p < pend; p += 256) {
        const int dd = (p >> 6) - dbase, h = p & 63;
        const float4* w1v = (const float4*)&w1s[dd * HID1];
        const float4* w2v = (const float4*)&w2s[h * 132];
        float acc = 0.f;
        #pragma unroll
        for (int k4 = 0; k4 < HID1 / 4; ++k4) {
            const float4 a = w1v[k4], b = w2v[k4];
            acc += a.x * b.x + a.y * b.y + a.z * b.z + a.w * b.w;
        }
        Bt[(size_t)p * KP + i] = f2bf(acc);
    }
}

// K0c: extra GEMM columns, bc computed inline:
// col 3328+j (j<64) = root[:,j]; col 3392+j = bc[:,j] = b2 + W2 @ b1 slice.
__global__ __launch_bounds__(256) void k_build_ext(const float* __restrict__ root,
                                                   const float* __restrict__ W2,
                                                   const float* __restrict__ b1,
                                                   const float* __restrict__ b2,
                                                   unsigned short* __restrict__ Bt) {
    const int j = blockIdx.x;        // 0..127
    const int i = threadIdx.x;       // 0..255
    if (i >= IN_DIM) return;
    float v;
    if (j < 64) {
        v = root[i * H_DIM + j];
    } else {
        const int jj = i * H_DIM + (j - 64);
        float acc = b2[jj];
        const float* w = W2 + (size_t)jj * HID1;
        #pragma unroll 8
        for (int k = 0; k < HID1; ++k) acc += w[k] * b1[k];
        v = acc;
    }
    Bt[(size_t)(NB + j) * KP + i] = f2bf(v);
}

// K1: x (fp32, [8192,235]) -> A (bf16, [8192,256] zero-padded)
__global__ __launch_bounds__(256) void k_build_a(const float* __restrict__ x,
                                                 unsigned short* __restrict__ A) {
    const int j = blockIdx.x * 256 + threadIdx.x;
    const int n = j >> 8, i = j & 255;
    A[j] = (i < IN_DIM) ? f2bf(x[n * IN_DIM + i]) : (unsigned short)0;
}

// ---------------------------------------------------------------------------
// K2: [8192,256] x [256,3584] GEMM with 256x256 block tiles (512 thr, 8 waves,
// each 128x64). Halves the logical A/Bt load traffic (113+113 -> 56+59 MB)
// vs 128x128 tiles — the r2-r4 evidence points at cache-hierarchy load BW as
// the binding constraint. Prefetch-after-barrier dbuf, XOR source swizzle,
// swapped MFMA operands (transposed D -> packed row-major stores).
// Tile x=13 is the special ext tile: cols 3328..3391 -> agg(+conv_b),
// 3392..3455 -> xb2, 3456..3583 garbage (Bt zero there; stores skipped).
__global__ __launch_bounds__(512, 2) void k_gemm(const unsigned short* __restrict__ A,
                                                 const unsigned short* __restrict__ Bt,
                                                 unsigned short* __restrict__ P,
                                                 float* __restrict__ agg,
                                                 float* __restrict__ xb2,
                                                 const float* __restrict__ conv_b) {
    __shared__ unsigned short As[2 * 256 * 32];   // 32 KB
    __shared__ unsigned short Bs[2 * 256 * 32];   // 32 KB
    const int t = threadIdx.x;
    const int m0 = blockIdx.y * 256, n0 = blockIdx.x * 256;
    const int wid = t >> 6, lane = t & 63;
    const int wm = wid & 1;          // 0..1 : 128-row half
    const int wn = wid >> 1;         // 0..3 : 64-col quarter
    const int q = lane >> 4, r16 = lane & 15;

    f32x4 acc[8][4] = {};

    auto stage = [&](int k0, int buf) {
        #pragma unroll
        for (int r = 0; r < 2; ++r) {
            const int idx = r * 512 + t;              // 0..1023 physical 16B slots
            const int row = idx >> 2;                 // 0..255
            const int lgrp = ((idx & 3) ^ ((row >> 1) & 3)) * 8;  // logical k-chunk
            const unsigned short* ga = &A[(size_t)(m0 + row) * KP + k0 + lgrp];
            const unsigned short* gb = &Bt[(size_t)(n0 + row) * KP + k0 + lgrp];
            char* la = (char*)As + buf * 16384 + r * 8192 + wid * 1024;
            char* lb = (char*)Bs + buf * 16384 + r * 8192 + wid * 1024;
            __builtin_amdgcn_global_load_lds(
                (const __attribute__((address_space(1))) unsigned int*)ga,
                (__attribute__((address_space(3))) unsigned int*)la, 16, 0, 0);
            __builtin_amdgcn_global_load_lds(
                (const __attribute__((address_space(1))) unsigned int*)gb,
                (__attribute__((address_space(3))) unsigned int*)lb, 16, 0, 0);
        }
    };

    stage(0, 0);
    const int pcq = (q ^ ((r16 >> 1) & 3)) * 8;       // physical chunk for logical q
    #pragma unroll
    for (int it = 0; it < 8; ++it) {
        __syncthreads();                              // drains prefetch for buf[it&1]
        if (it < 7) stage((it + 1) * 32, (it + 1) & 1);
        const int bo = (it & 1) * 8192;               // buffer offset in shorts
        bf16x8 af[8], bfr[4];
        #pragma unroll
        for (int mi = 0; mi < 8; ++mi)
            af[mi] = *(const bf16x8*)(&As[bo + (wm * 128 + mi * 16 + r16) * 32 + pcq]);
        #pragma unroll
        for (int ni = 0; ni < 4; ++ni)
            bfr[ni] = *(const bf16x8*)(&Bs[bo + (wn * 64 + ni * 16 + r16) * 32 + pcq]);
        #pragma unroll
        for (int mi = 0; mi < 8; ++mi)
            #pragma unroll
            for (int ni = 0; ni < 4; ++ni)
                acc[mi][ni] = __builtin_amdgcn_mfma_f32_16x16x32_bf16(
                    bfr[ni], af[mi], acc[mi][ni], 0, 0, 0);   // transposed D
    }

    // Transposed D: lane (q,r16) holds rows m = mi*16+r16, cols n = ni*16+q*4..+3
    if (n0 < NB) {
        #pragma unroll
        for (int mi = 0; mi < 8; ++mi)
            #pragma unroll
            for (int ni = 0; ni < 4; ++ni) {
                const int row = m0 + wm * 128 + mi * 16 + r16;
                const int col = n0 + wn * 64 + ni * 16 + q * 4;
                union { unsigned short us[4]; uint2 u2; } pk;
                #pragma unroll
                for (int rr = 0; rr < 4; ++rr) pk.us[rr] = f2bf(acc[mi][ni][rr]);
                *(uint2*)(&P[(size_t)row * NB + col]) = pk.u2;
            }
    } else if (wn < 2) {
        #pragma unroll
        for (int mi = 0; mi < 8; ++mi)
            #pragma unroll
            for (int ni = 0; ni < 4; ++ni) {
                const int row = m0 + wm * 128 + mi * 16 + r16;
                const int cl = ni * 16 + q * 4;       // 0..63 within the half
                if (wn == 0) {
                    const float4 cb = *(const float4*)&conv_b[cl];
                    float4 v;
                    v.x = acc[mi][ni][0] + cb.x; v.y = acc[mi][ni][1] + cb.y;
                    v.z = acc[mi][ni][2] + cb.z; v.w = acc[mi][ni][3] + cb.w;
                    *(float4*)(&agg[row * H_DIM + cl]) = v;
                } else {
                    float4 v;
                    v.x = acc[mi][ni][0]; v.y = acc[mi][ni][1];
                    v.z = acc[mi][ni][2]; v.w = acc[mi][ni][3];
                    *(float4*)(&xb2[row * H_DIM + cl]) = v;
                }
            }
    }
}

// ---------------------------------------------------------------------------
// K4: per edge (one wave, lane=h). All 52 P-row loads in flight.
__global__ __launch_bounds__(256) void k_edge(const int* __restrict__ ei,
                                              const float* __restrict__ ea,
                                              const unsigned short* __restrict__ P,
                                              const float* __restrict__ xb2,
                                              float* __restrict__ agg) {
    const int e = (blockIdx.x * 256 + threadIdx.x) >> 6;
    const int h = threadIdx.x & 63;
    if (e >= N_EDGES) return;
    const int s = ei[e], dst = ei[N_EDGES + e];
    const unsigned short* Pr = P + (size_t)s * NB + h;
    const float* ear = ea + (size_t)e * ED_DIM;

    float eav[ED_DIM];
    #pragma unroll
    for (int d4 = 0; d4 < ED_DIM / 4; ++d4)
        *(float4*)&eav[d4 * 4] = *(const float4*)&ear[d4 * 4];

    unsigned short pv[ED_DIM];
    #pragma unroll
    for (int d = 0; d < ED_DIM; ++d) pv[d] = Pr[d * H_DIM];

    float acc = xb2[s * H_DIM + h];
    #pragma unroll
    for (int d = 0; d < ED_DIM; ++d) acc += eav[d] * bf2f(pv[d]);
    atomicAdd(&agg[dst * H_DIM + h], acc);
}

// K5: out = relu(agg); mean-pool accumulate per graph
__global__ __launch_bounds__(256) void k_pool(const float* __restrict__ agg,
                                              const int* __restrict__ batch,
                                              float* __restrict__ psum,
                                              float* __restrict__ pcnt) {
    const int n = (blockIdx.x * 256 + threadIdx.x) >> 6;
    const int h = threadIdx.x & 63;
    if (n >= N_NODES) return;
    const float v = fmaxf(agg[n * H_DIM + h], 0.f);
    const int g = batch[n];
    atomicAdd(&psum[g * H_DIM + h], v);
    if (h == 0) atomicAdd(&pcnt[g], 1.0f);
}

// K6: MLP head, one block per graph
__global__ __launch_bounds__(256) void k_head(const float* __restrict__ psum,
                                              const float* __restrict__ pcnt,
                                              const float* __restrict__ fw1, const float* __restrict__ fb1,
                                              const float* __restrict__ fw2, const float* __restrict__ fb2,
                                              const float* __restrict__ fw3, const float* __restrict__ fb3,
                                              const float* __restrict__ fw4, const float* __restrict__ fb4,
                                              float* __restrict__ out) {
    __shared__ float sp[64], s1[128], s2[256], s3[128];
    const int g = blockIdx.x, t = threadIdx.x;
    if (t < 64) sp[t] = psum[g * 64 + t] / fmaxf(pcnt[g], 1.0f);
    __syncthreads();
    if (t < 128) {
        float a = fb1[t];
        const float* w = fw1 + t * 64;
        #pragma unroll 8
        for (int k = 0; k < 64; ++k) a += sp[k] * w[k];
        s1[t] = fmaxf(a, 0.f);
    }
    __syncthreads();
    {
        float a = fb2[t];
        const float* w = fw2 + t * 128;
        #pragma unroll 8
        for (int k = 0; k < 128; ++k) a += s1[k] * w[k];
        s2[t] = fmaxf(a, 0.f);
    }
    __syncthreads();
    if (t < 128) {
        float a = fb3[t];
        const float* w = fw3 + t * 256;
        #pragma unroll 8
        for (int k = 0; k < 256; ++k) a += s2[k] * w[k];
        s3[t] = fmaxf(a, 0.f);
    }
    __syncthreads();
    if (t < 64) {
        float p = s3[t] * fw4[t] + s3[t + 64] * fw4[t + 64];
        #pragma unroll
        for (int off = 32; off > 0; off >>= 1) p += __shfl_down(p, off);
        if (t == 0) out[g] = p + fb4[0];
    }
}

// ---------------------------------------------------------------------------
extern "C" void kernel_launch(void* const* d_in, const int* in_sizes, int n_in,
                              void* d_out, int out_size, void* d_ws, size_t ws_size,
                              hipStream_t stream) {
    const float* x      = (const float*)d_in[0];
    const int*   ei     = (const int*)d_in[1];
    const float* ea     = (const float*)d_in[2];
    const int*   batch  = (const int*)d_in[3];
    const float* W1     = (const float*)d_in[4];
    const float* b1     = (const float*)d_in[5];
    const float* W2     = (const float*)d_in[6];
    const float* b2     = (const float*)d_in[7];
    const float* root   = (const float*)d_in[8];
    const float* conv_b = (const float*)d_in[9];
    const float* fw1 = (const float*)d_in[10]; const float* fb1 = (const float*)d_in[11];
    const float* fw2 = (const float*)d_in[12]; const float* fb2 = (const float*)d_in[13];
    const float* fw3 = (const float*)d_in[14]; const float* fb3 = (const float*)d_in[15];
    const float* fw4 = (const float*)d_in[16]; const float* fb4 = (const float*)d_in[17];
    float* out = (float*)d_out;

    char* ws = (char*)d_ws;
    // workspace layout (16B-aligned), total ~64.9 MB
    unsigned short* A   = (unsigned short*)(ws);             // 8192*256*2   = 4,194,304
    unsigned short* Bt  = (unsigned short*)(ws + 4194304);   // 3584*256*2   = 1,835,008
    unsigned short* P   = (unsigned short*)(ws + 6029312);   // 8192*3328*2  = 54,525,952
    float* agg  = (float*)(ws + 60555264);                   // 8192*64*4    = 2,097,152
    float* xb2  = (float*)(ws + 62652416);                   // 8192*64*4    = 2,097,152
    float* psum = (float*)(ws + 64749568);                   // 512*64*4     = 131,072
    float* pcnt = (float*)(ws + 64880640);                   // 512*4        = 2,048

    // Bt must start zeroed (pad cols i>=235 and rows >=3456); psum/pcnt -> one memset
    hipMemsetAsync(Bt, 0, (size_t)NBP * KP * sizeof(unsigned short), stream);
    hipMemsetAsync(psum, 0, (size_t)(N_GRAPHS * H_DIM + N_GRAPHS) * sizeof(float), stream);

    k_build_bt<<<dim3(IN_DIM, 4), dim3(256), 0, stream>>>(W1, W2, Bt);
    k_build_ext<<<dim3(128), dim3(256), 0, stream>>>(root, W2, b1, b2, Bt);
    k_build_a<<<dim3(N_NODES), dim3(256), 0, stream>>>(x, A);
    k_gemm<<<dim3(NBP / 256, N_NODES / 256), dim3(512), 0, stream>>>(A, Bt, P, agg, xb2, conv_b);
    k_edge<<<dim3(N_EDGES / 4), dim3(256), 0, stream>>>(ei, ea, P, xb2, agg);
    k_pool<<<dim3(N_NODES / 4), dim3(256), 0, stream>>>(agg, batch, psum, pcnt);
    k_head<<<dim3(N_GRAPHS), dim3(256), 0, stream>>>(psum, pcnt, fw1, fb1, fw2, fb2, fw3, fb3, fw4, fb4, out);
}